// Round 9
// baseline (302.044 us; speedup 1.0000x reference)
//
#include <hip/hip_runtime.h>
#include <math.h>

#define B_  2
#define S_  2048
#define D_  1024
#define H_  16
#define DH_ 64

typedef unsigned short u16;
typedef unsigned int   u32;
typedef _Float16       f16;
typedef _Float16 half8  __attribute__((ext_vector_type(8)));
typedef _Float16 half4  __attribute__((ext_vector_type(4)));
typedef float    f32x4  __attribute__((ext_vector_type(4)));

#if __has_builtin(__builtin_amdgcn_exp2f)
#define EXP2(x) __builtin_amdgcn_exp2f(x)
#else
#define EXP2(x) exp2f(x)
#endif

__device__ __forceinline__ u16 h_bits(f16 h){ return __builtin_bit_cast(u16, h); }

// ---------------------------------------------------------------------------
// Kernel 1: prep = split_x + convert_w fused (block-uniform path switch).
// blocks [0,4096): X fp32 -> Xhi/Xlo fp16 2-term split.
// blocks [4096,4864): W fp32 [which][h][d][e] -> Wt fp16 [which*H+h][e][d],
// scaled x64 (keeps W in f16 normal range; /64 folded into proj epilogue).
// ---------------------------------------------------------------------------
__global__ __launch_bounds__(256) void prep_kernel(
    const float* __restrict__ X,
    const float* __restrict__ Wq, const float* __restrict__ Wk,
    const float* __restrict__ Wv,
    u16* __restrict__ Xhi, u16* __restrict__ Xlo, u16* __restrict__ Wt)
{
    __shared__ float Wf[64][65];
    const int bid = blockIdx.x;
    const int c   = threadIdx.x;

    if (bid < 4096){
        const int idx = bid * 256 + c;
        float4 v = ((const float4*)X)[idx];
        float fv[4] = {v.x, v.y, v.z, v.w};
        u16 hh[4], ll[4];
        #pragma unroll
        for (int j = 0; j < 4; ++j){
            f16 hi = (f16)fv[j];
            hh[j] = h_bits(hi);
            ll[j] = h_bits((f16)(fv[j] - (float)hi));
        }
        uint2 ph, pl;
        ph.x = hh[0] | ((u32)hh[1] << 16);
        ph.y = hh[2] | ((u32)hh[3] << 16);
        pl.x = ll[0] | ((u32)ll[1] << 16);
        pl.y = ll[2] | ((u32)ll[3] << 16);
        ((uint2*)Xhi)[idx] = ph;
        ((uint2*)Xlo)[idx] = pl;
        return;
    }

    const int wb = bid - 4096;          // 0..767
    const int d0 = (wb & 15) * 64;
    const int h  = (wb >> 4) & 15;
    const int which = wb >> 8;
    const float* src = (which == 0) ? Wq : (which == 1) ? Wk : Wv;
    src += (size_t)h * D_ * DH_;

    #pragma unroll
    for (int it = 0; it < 4; ++it){
        int d  = (c >> 4) + 16 * it;
        int e4 = (c & 15) * 4;
        float4 v = *(const float4*)(src + (size_t)(d0 + d) * DH_ + e4);
        Wf[d][e4+0] = v.x; Wf[d][e4+1] = v.y; Wf[d][e4+2] = v.z; Wf[d][e4+3] = v.w;
    }
    __syncthreads();
    u16* dst = Wt + (size_t)(which * H_ + h) * DH_ * D_;
    #pragma unroll
    for (int it = 0; it < 4; ++it){
        int e  = (c >> 4) + 16 * it;
        int d4 = (c & 15) * 4;
        u16 q[4];
        #pragma unroll
        for (int j = 0; j < 4; ++j)
            q[j] = h_bits((f16)(Wf[d4 + j][e] * 64.0f));
        u32* p = (u32*)(dst + (size_t)e * D_ + d0 + d4);
        p[0] = q[0] | ((u32)q[1] << 16);
        p[1] = q[2] | ((u32)q[3] << 16);
    }
}

// ---------------------------------------------------------------------------
// Kernel 2: QKV projection as ONE flat GEMM: C[4096][3072] = X[4096][1024]·W
// X pre-split fp16 hi/lo, W fp16 (x64).  128x128 tiles, 4 waves, BK=32.
// LDS stride 40 f16 = 20 dw (valid: rows are 32 elements) -> conflict-free,
// all LDS ops 16B-aligned b128.  Register prefetch of next k-tile.
// Epilogue: Q/K written [bh][s][e] coalesced; V written TRANSPOSED to
// Vt[bh][e][t] directly (4 consecutive s per thread -> aligned 8B stores).
// ---------------------------------------------------------------------------
#define PKS 40

__global__ __launch_bounds__(256, 3) void proj_kernel(
    const u16* __restrict__ Xhi, const u16* __restrict__ Xlo,
    const u16* __restrict__ Wt,
    const float* __restrict__ bq, const float* __restrict__ bk,
    const float* __restrict__ bv,
    f16* __restrict__ Qh, f16* __restrict__ Kh, f16* __restrict__ Vt)
{
    __shared__ u16 XsHi[128 * PKS], XsLo[128 * PKS], Bs[128 * PKS];

    const int tid  = threadIdx.x;
    const int lane = tid & 63;
    const int w    = tid >> 6;
    const int quad = lane >> 4;
    const int ln   = lane & 15;
    const int wr   = (w >> 1) * 64;
    const int wc   = (w & 1) * 64;
    const int m0   = blockIdx.x * 128;
    const int c0   = blockIdx.y * 128;

    const int sr  = tid >> 2;          // 0..63
    const int sch = (tid & 3) * 8;     // 0,8,16,24

    const u16* xh0 = Xhi + (size_t)(m0 + sr) * D_ + sch;
    const u16* xh1 = xh0 + (size_t)64 * D_;
    const u16* xl0 = Xlo + (size_t)(m0 + sr) * D_ + sch;
    const u16* xl1 = xl0 + (size_t)64 * D_;
    const u16* wb0 = Wt  + (size_t)(c0 + sr) * D_ + sch;
    const u16* wb1 = wb0 + (size_t)64 * D_;

    uint4 rh0 = *(const uint4*)xh0, rh1 = *(const uint4*)xh1;
    uint4 rl0 = *(const uint4*)xl0, rl1 = *(const uint4*)xl1;
    uint4 rw0 = *(const uint4*)wb0, rw1 = *(const uint4*)wb1;

    f32x4 acc[4][4];
    #pragma unroll
    for (int i = 0; i < 4; ++i)
        #pragma unroll
        for (int j = 0; j < 4; ++j)
            acc[i][j] = (f32x4){0.f, 0.f, 0.f, 0.f};

    for (int k0 = 0; k0 < D_; k0 += 32){
        __syncthreads();
        *(uint4*)&XsHi[sr * PKS + sch]        = rh0;
        *(uint4*)&XsHi[(sr + 64) * PKS + sch] = rh1;
        *(uint4*)&XsLo[sr * PKS + sch]        = rl0;
        *(uint4*)&XsLo[(sr + 64) * PKS + sch] = rl1;
        *(uint4*)&Bs[sr * PKS + sch]          = rw0;
        *(uint4*)&Bs[(sr + 64) * PKS + sch]   = rw1;
        const int kn = k0 + 32;
        if (kn < D_){
            rh0 = *(const uint4*)(xh0 + kn); rh1 = *(const uint4*)(xh1 + kn);
            rl0 = *(const uint4*)(xl0 + kn); rl1 = *(const uint4*)(xl1 + kn);
            rw0 = *(const uint4*)(wb0 + kn); rw1 = *(const uint4*)(wb1 + kn);
        }
        __syncthreads();

        half8 ahi[4], alo[4], bf[4];
        #pragma unroll
        for (int mt = 0; mt < 4; ++mt){
            int row = wr + 16 * mt + ln;
            ahi[mt] = __builtin_bit_cast(half8, *(const uint4*)&XsHi[row * PKS + quad * 8]);
            alo[mt] = __builtin_bit_cast(half8, *(const uint4*)&XsLo[row * PKS + quad * 8]);
        }
        #pragma unroll
        for (int nt = 0; nt < 4; ++nt)
            bf[nt] = __builtin_bit_cast(half8,
                *(const uint4*)&Bs[(wc + 16 * nt + ln) * PKS + quad * 8]);
        #pragma unroll
        for (int mt = 0; mt < 4; ++mt)
            #pragma unroll
            for (int nt = 0; nt < 4; ++nt){
                acc[mt][nt] = __builtin_amdgcn_mfma_f32_16x16x32_f16(ahi[mt], bf[nt], acc[mt][nt], 0, 0, 0);
                acc[mt][nt] = __builtin_amdgcn_mfma_f32_16x16x32_f16(alo[mt], bf[nt], acc[mt][nt], 0, 0, 0);
            }
    }

    const float QSCALE = 0.125f * 1.44269504088896340736f;
    const float INV64  = 0.015625f;
    #pragma unroll
    for (int nt = 0; nt < 4; ++nt){
        int colg  = c0 + wc + 16 * nt + ln;
        int which = colg >> 10;          // uniform within the 16-col group
        int h     = (colg >> 6) & 15;    // uniform within the 16-col group
        int e     = colg & 63;
        const float* bp = (which == 0) ? bq : (which == 1) ? bk : bv;
        float bias = bp[h * DH_ + e];
        if (which < 2){
            f16* op = (which == 0) ? Qh : Kh;
            float scale = (which == 0) ? QSCALE : 1.0f;
            #pragma unroll
            for (int mt = 0; mt < 4; ++mt)
                #pragma unroll
                for (int r = 0; r < 4; ++r){
                    int sg = m0 + wr + 16 * mt + 4 * quad + r;
                    int b  = sg >> 11;
                    int s  = sg & (S_ - 1);
                    float val = (acc[mt][nt][r] * INV64 + bias) * scale;
                    op[((size_t)(b * H_ + h) * S_ + s) * DH_ + e] = (f16)val;
                }
        } else {
            // V: write transposed Vt[bh][e][t]; 4 consecutive s -> 8B store
            #pragma unroll
            for (int mt = 0; mt < 4; ++mt){
                int sg0 = m0 + wr + 16 * mt + 4 * quad;
                int b   = sg0 >> 11;
                int s0  = sg0 & (S_ - 1);
                u16 p[4];
                #pragma unroll
                for (int r = 0; r < 4; ++r)
                    p[r] = h_bits((f16)(acc[mt][nt][r] * INV64 + bias));
                uint2 pk;
                pk.x = p[0] | ((u32)p[1] << 16);
                pk.y = p[2] | ((u32)p[3] << 16);
                *(uint2*)((u16*)Vt + ((size_t)((b * H_ + h) * DH_ + e)) * S_ + s0) = pk;
            }
        }
    }
}

// ---------------------------------------------------------------------------
// Kernel 3: attention.  R9: 128-wide K-tiles (16 barrier pairs) but the
// score tile is processed as TWO sequential 64-column halves, each with its
// own sc[4] (16 VGPRs live) -- R8's sc[8] blew the 128-VGPR cap from
// __launch_bounds__(256,4) and spilled ~434 MB/dispatch to scratch.
// Work pairing: waves 0-1 own q-rows [32i,32i+32), waves 2-3 own
// [2048-32(i+1),...) -> uniform block duration.
// S^T = K·Q^T via mfma_16x16x32_f16; C-layout of S^T is the PV A-layout,
// so P stays in registers (exp2 -> tril mask -> cvt f16 -> PV).
// Denominator over ALL t (reference softmaxes the full row); PV only t<=s
// (post-softmax tril, no renorm).  No max-tracking (logits provably tiny;
// base-2 exp, 0.125*log2e folded into Q upstream).
// grid (32 pairs, 16 h, 2 b), block 256.  LDS 35 KB -> 4 blocks/CU.
// ---------------------------------------------------------------------------
#define AKS 72
#define VKS 136

__global__ __launch_bounds__(256, 4) void attn_kernel(
    const f16* __restrict__ Qh, const f16* __restrict__ Kh,
    const f16* __restrict__ Vt, float* __restrict__ Out)
{
    __shared__ u16 Ks[128 * AKS];   // K tile [t][e]
    __shared__ u16 Vs[64 * VKS];    // V tile [e][t]

    const int tid  = threadIdx.x;
    const int lane = tid & 63;
    const int w    = tid >> 6;
    const int quad = lane >> 4;
    const int ln   = lane & 15;
    const int i    = blockIdx.x;            // pair index
    const int h    = blockIdx.y;
    const int b    = blockIdx.z;
    const int bh   = b * H_ + h;
    const int sub  = w & 1;
    const int qbase = (w >> 1) ? (S_ - 32 * (i + 1) + 16 * sub)
                               : (32 * i + 16 * sub);
    const int vmax  = S_ - 32 * i - 1;      // highest t any wave's PV needs

    const u16* Qg = (const u16*)Qh + (size_t)bh * S_ * DH_;
    const u16* Kg = (const u16*)Kh + (size_t)bh * S_ * DH_;
    const u16* Vg = (const u16*)Vt + (size_t)bh * DH_ * S_;

    // Q fragments straight from global (B-operand: n=q=ln, k=d=32ks+8quad+j)
    half8 qf[2];
    #pragma unroll
    for (int ks = 0; ks < 2; ++ks)
        qf[ks] = __builtin_bit_cast(half8,
            *(const uint4*)(Qg + (size_t)(qbase + ln) * DH_ + 32 * ks + 8 * quad));

    // staging coords
    const int kr = tid >> 3;          // K rows kr+32j (j=0..3)
    const int kc = (tid & 7) * 8;
    const int er = tid >> 2;          // V e-row 0..63
    const int vj = (tid & 3) * 8;     // V col chunks vj + 32j

    // prefetch tile 0
    uint4 kP[4], vP[4];
    #pragma unroll
    for (int j = 0; j < 4; ++j){
        kP[j] = *(const uint4*)(Kg + (size_t)(kr + 32 * j) * DH_ + kc);
        vP[j] = *(const uint4*)(Vg + (size_t)er * S_ + vj + 32 * j);
    }

    float l_r = 0.f;
    f32x4 o_acc[4];
    #pragma unroll
    for (int nt = 0; nt < 4; ++nt) o_acc[nt] = (f32x4){0.f, 0.f, 0.f, 0.f};

    const int qrow   = qbase + ln;     // this lane's q (n-dim)
    const int pv_lim = qbase + 15;     // wave-uniform PV bound

    for (int t0 = 0; t0 < S_; t0 += 128){
        __syncthreads();               // all waves done reading prev tile
        #pragma unroll
        for (int j = 0; j < 4; ++j)
            *(uint4*)&Ks[(kr + 32 * j) * AKS + kc] = kP[j];
        if (t0 <= vmax){
            #pragma unroll
            for (int j = 0; j < 4; ++j)
                *(uint4*)&Vs[er * VKS + vj + 32 * j] = vP[j];
        }
        // prefetch tile t0+128 (hidden behind this tile's compute)
        const int tn = t0 + 128;
        if (tn < S_){
            #pragma unroll
            for (int j = 0; j < 4; ++j)
                kP[j] = *(const uint4*)(Kg + (size_t)(tn + kr + 32 * j) * DH_ + kc);
            if (tn <= vmax){
                #pragma unroll
                for (int j = 0; j < 4; ++j)
                    vP[j] = *(const uint4*)(Vg + (size_t)er * S_ + tn + vj + 32 * j);
            }
        }
        __syncthreads();               // LDS tile ready

        // two 64-column halves; sc[4] live per half (register-budget fix)
        #pragma unroll
        for (int hf = 0; hf < 2; ++hf){
            const int tb0 = t0 + 64 * hf;

            f32x4 sc[4];
            #pragma unroll
            for (int mt = 0; mt < 4; ++mt) sc[mt] = (f32x4){0.f, 0.f, 0.f, 0.f};
            #pragma unroll
            for (int ks = 0; ks < 2; ++ks)
                #pragma unroll
                for (int mt = 0; mt < 4; ++mt){
                    half8 kf = __builtin_bit_cast(half8,
                        *(const uint4*)&Ks[(64 * hf + 16 * mt + ln) * AKS + 32 * ks + 8 * quad]);
                    sc[mt] = __builtin_amdgcn_mfma_f32_16x16x32_f16(kf, qf[ks], sc[mt], 0, 0, 0);
                }

            // p = exp2(s); denominator = plain running row-sum over ALL t
            #pragma unroll
            for (int mt = 0; mt < 4; ++mt)
                #pragma unroll
                for (int r = 0; r < 4; ++r)
                    sc[mt][r] = EXP2(sc[mt][r]);
            float s = ((sc[0][0] + sc[0][1] + sc[0][2] + sc[0][3]) +
                       (sc[1][0] + sc[1][1] + sc[1][2] + sc[1][3])) +
                      ((sc[2][0] + sc[2][1] + sc[2][2] + sc[2][3]) +
                       (sc[3][0] + sc[3][1] + sc[3][2] + sc[3][3]));
            s += __shfl_xor(s, 16);
            s += __shfl_xor(s, 32);
            l_r += s;

            // PV per 16-t subtile (wave-uniform skip above the diagonal)
            #pragma unroll
            for (int mt = 0; mt < 4; ++mt){
                if (tb0 + 16 * mt <= pv_lim){
                    int tb = tb0 + 16 * mt + 4 * quad;
                    half4 pf;
                    #pragma unroll
                    for (int r = 0; r < 4; ++r)
                        pf[r] = (tb + r > qrow) ? (f16)0.f : (f16)sc[mt][r];
                    #pragma unroll
                    for (int nt = 0; nt < 4; ++nt){
                        half4 vf = __builtin_bit_cast(half4,
                            *(const uint2*)&Vs[(16 * nt + ln) * VKS + 64 * hf + 16 * mt + 4 * quad]);
                        o_acc[nt] = __builtin_amdgcn_mfma_f32_16x16x16f16(pf, vf, o_acc[nt], 0, 0, 0);
                    }
                }
            }
        }
    }

    // epilogue: o rows at q = qbase+4quad+r; l lives at lane ln=row
    #pragma unroll
    for (int r = 0; r < 4; ++r){
        float lv  = __shfl(l_r, (lane & 48) | (4 * quad + r));
        float inv = 1.0f / lv;
        int sg = qbase + 4 * quad + r;
        float* op = Out + ((size_t)b * S_ + sg) * D_ + h * DH_;
        #pragma unroll
        for (int nt = 0; nt < 4; ++nt)
            op[16 * nt + ln] = o_acc[nt][r] * inv;
    }
}

// ---------------------------------------------------------------------------
extern "C" void kernel_launch(void* const* d_in, const int* in_sizes, int n_in,
                              void* d_out, int out_size, void* d_ws, size_t ws_size,
                              hipStream_t stream)
{
    const float* X  = (const float*)d_in[0];
    const float* Wq = (const float*)d_in[1];
    const float* bq = (const float*)d_in[2];
    const float* Wk = (const float*)d_in[3];
    const float* bk = (const float*)d_in[4];
    const float* Wv = (const float*)d_in[5];
    const float* bv = (const float*)d_in[6];
    float* out = (float*)d_out;

    // workspace (46 MiB): Wt | Qh | Kh | Vt | Xhi | Xlo
    u16* Wt  = (u16*)d_ws;                    // 3,145,728 u16
    f16* Qh  = (f16*)(Wt + 3145728);
    f16* Kh  = Qh + 4194304;
    f16* Vt  = Kh + 4194304;
    u16* Xhi = (u16*)(Vt + 4194304);
    u16* Xlo = Xhi + 4194304;

    prep_kernel<<<dim3(4096 + 768), 256, 0, stream>>>(X, Wq, Wk, Wv, Xhi, Xlo, Wt);
    proj_kernel<<<dim3(32, 24), 256, 0, stream>>>(Xhi, Xlo, Wt, bq, bk, bv, Qh, Kh, Vt);
    attn_kernel<<<dim3(32, 16, 2), 256, 0, stream>>>(Qh, Kh, Vt, out);
}

// Round 10
// 195.121 us; speedup vs baseline: 1.5480x; 1.5480x over previous
//
#include <hip/hip_runtime.h>
#include <math.h>

#define B_  2
#define S_  2048
#define D_  1024
#define H_  16
#define DH_ 64

typedef unsigned short u16;
typedef unsigned int   u32;
typedef _Float16       f16;
typedef _Float16 half8  __attribute__((ext_vector_type(8)));
typedef _Float16 half4  __attribute__((ext_vector_type(4)));
typedef float    f32x4  __attribute__((ext_vector_type(4)));

#if __has_builtin(__builtin_amdgcn_exp2f)
#define EXP2(x) __builtin_amdgcn_exp2f(x)
#else
#define EXP2(x) exp2f(x)
#endif

__device__ __forceinline__ u16 h_bits(f16 h){ return __builtin_bit_cast(u16, h); }

// ---------------------------------------------------------------------------
// Kernel 1: prep = split_x + convert_w fused (block-uniform path switch).
// blocks [0,4096): X fp32 -> Xhi/Xlo fp16 2-term split.
// blocks [4096,4864): W fp32 [which][h][d][e] -> Wt fp16 [which*H+h][e][d],
// scaled x64 (keeps W in f16 normal range; /64 folded into proj epilogue).
// ---------------------------------------------------------------------------
__global__ __launch_bounds__(256) void prep_kernel(
    const float* __restrict__ X,
    const float* __restrict__ Wq, const float* __restrict__ Wk,
    const float* __restrict__ Wv,
    u16* __restrict__ Xhi, u16* __restrict__ Xlo, u16* __restrict__ Wt)
{
    __shared__ float Wf[64][65];
    const int bid = blockIdx.x;
    const int c   = threadIdx.x;

    if (bid < 4096){
        const int idx = bid * 256 + c;
        float4 v = ((const float4*)X)[idx];
        float fv[4] = {v.x, v.y, v.z, v.w};
        u16 hh[4], ll[4];
        #pragma unroll
        for (int j = 0; j < 4; ++j){
            f16 hi = (f16)fv[j];
            hh[j] = h_bits(hi);
            ll[j] = h_bits((f16)(fv[j] - (float)hi));
        }
        uint2 ph, pl;
        ph.x = hh[0] | ((u32)hh[1] << 16);
        ph.y = hh[2] | ((u32)hh[3] << 16);
        pl.x = ll[0] | ((u32)ll[1] << 16);
        pl.y = ll[2] | ((u32)ll[3] << 16);
        ((uint2*)Xhi)[idx] = ph;
        ((uint2*)Xlo)[idx] = pl;
        return;
    }

    const int wb = bid - 4096;          // 0..767
    const int d0 = (wb & 15) * 64;
    const int h  = (wb >> 4) & 15;
    const int which = wb >> 8;
    const float* src = (which == 0) ? Wq : (which == 1) ? Wk : Wv;
    src += (size_t)h * D_ * DH_;

    #pragma unroll
    for (int it = 0; it < 4; ++it){
        int d  = (c >> 4) + 16 * it;
        int e4 = (c & 15) * 4;
        float4 v = *(const float4*)(src + (size_t)(d0 + d) * DH_ + e4);
        Wf[d][e4+0] = v.x; Wf[d][e4+1] = v.y; Wf[d][e4+2] = v.z; Wf[d][e4+3] = v.w;
    }
    __syncthreads();
    u16* dst = Wt + (size_t)(which * H_ + h) * DH_ * D_;
    #pragma unroll
    for (int it = 0; it < 4; ++it){
        int e  = (c >> 4) + 16 * it;
        int d4 = (c & 15) * 4;
        u16 q[4];
        #pragma unroll
        for (int j = 0; j < 4; ++j)
            q[j] = h_bits((f16)(Wf[d4 + j][e] * 64.0f));
        u32* p = (u32*)(dst + (size_t)e * D_ + d0 + d4);
        p[0] = q[0] | ((u32)q[1] << 16);
        p[1] = q[2] | ((u32)q[3] << 16);
    }
}

// ---------------------------------------------------------------------------
// Kernel 2: QKV projection as ONE flat GEMM: C[4096][3072] = X[4096][1024]·W
// X pre-split fp16 hi/lo, W fp16 (x64).  128x128 tiles, 4 waves, BK=32.
// LDS stride 40 f16 = 20 dw (valid: rows are 32 elements) -> conflict-free,
// all LDS ops 16B-aligned b128.  Register prefetch of next k-tile.
// Epilogue: Q/K written [bh][s][e] coalesced; V written TRANSPOSED to
// Vt[bh][e][t] directly (4 consecutive s per thread -> aligned 8B stores).
// ---------------------------------------------------------------------------
#define PKS 40

__global__ __launch_bounds__(256, 3) void proj_kernel(
    const u16* __restrict__ Xhi, const u16* __restrict__ Xlo,
    const u16* __restrict__ Wt,
    const float* __restrict__ bq, const float* __restrict__ bk,
    const float* __restrict__ bv,
    f16* __restrict__ Qh, f16* __restrict__ Kh, f16* __restrict__ Vt)
{
    __shared__ u16 XsHi[128 * PKS], XsLo[128 * PKS], Bs[128 * PKS];

    const int tid  = threadIdx.x;
    const int lane = tid & 63;
    const int w    = tid >> 6;
    const int quad = lane >> 4;
    const int ln   = lane & 15;
    const int wr   = (w >> 1) * 64;
    const int wc   = (w & 1) * 64;
    const int m0   = blockIdx.x * 128;
    const int c0   = blockIdx.y * 128;

    const int sr  = tid >> 2;          // 0..63
    const int sch = (tid & 3) * 8;     // 0,8,16,24

    const u16* xh0 = Xhi + (size_t)(m0 + sr) * D_ + sch;
    const u16* xh1 = xh0 + (size_t)64 * D_;
    const u16* xl0 = Xlo + (size_t)(m0 + sr) * D_ + sch;
    const u16* xl1 = xl0 + (size_t)64 * D_;
    const u16* wb0 = Wt  + (size_t)(c0 + sr) * D_ + sch;
    const u16* wb1 = wb0 + (size_t)64 * D_;

    uint4 rh0 = *(const uint4*)xh0, rh1 = *(const uint4*)xh1;
    uint4 rl0 = *(const uint4*)xl0, rl1 = *(const uint4*)xl1;
    uint4 rw0 = *(const uint4*)wb0, rw1 = *(const uint4*)wb1;

    f32x4 acc[4][4];
    #pragma unroll
    for (int i = 0; i < 4; ++i)
        #pragma unroll
        for (int j = 0; j < 4; ++j)
            acc[i][j] = (f32x4){0.f, 0.f, 0.f, 0.f};

    for (int k0 = 0; k0 < D_; k0 += 32){
        __syncthreads();
        *(uint4*)&XsHi[sr * PKS + sch]        = rh0;
        *(uint4*)&XsHi[(sr + 64) * PKS + sch] = rh1;
        *(uint4*)&XsLo[sr * PKS + sch]        = rl0;
        *(uint4*)&XsLo[(sr + 64) * PKS + sch] = rl1;
        *(uint4*)&Bs[sr * PKS + sch]          = rw0;
        *(uint4*)&Bs[(sr + 64) * PKS + sch]   = rw1;
        const int kn = k0 + 32;
        if (kn < D_){
            rh0 = *(const uint4*)(xh0 + kn); rh1 = *(const uint4*)(xh1 + kn);
            rl0 = *(const uint4*)(xl0 + kn); rl1 = *(const uint4*)(xl1 + kn);
            rw0 = *(const uint4*)(wb0 + kn); rw1 = *(const uint4*)(wb1 + kn);
        }
        __syncthreads();

        half8 ahi[4], alo[4], bf[4];
        #pragma unroll
        for (int mt = 0; mt < 4; ++mt){
            int row = wr + 16 * mt + ln;
            ahi[mt] = __builtin_bit_cast(half8, *(const uint4*)&XsHi[row * PKS + quad * 8]);
            alo[mt] = __builtin_bit_cast(half8, *(const uint4*)&XsLo[row * PKS + quad * 8]);
        }
        #pragma unroll
        for (int nt = 0; nt < 4; ++nt)
            bf[nt] = __builtin_bit_cast(half8,
                *(const uint4*)&Bs[(wc + 16 * nt + ln) * PKS + quad * 8]);
        #pragma unroll
        for (int mt = 0; mt < 4; ++mt)
            #pragma unroll
            for (int nt = 0; nt < 4; ++nt){
                acc[mt][nt] = __builtin_amdgcn_mfma_f32_16x16x32_f16(ahi[mt], bf[nt], acc[mt][nt], 0, 0, 0);
                acc[mt][nt] = __builtin_amdgcn_mfma_f32_16x16x32_f16(alo[mt], bf[nt], acc[mt][nt], 0, 0, 0);
            }
    }

    const float QSCALE = 0.125f * 1.44269504088896340736f;
    const float INV64  = 0.015625f;
    #pragma unroll
    for (int nt = 0; nt < 4; ++nt){
        int colg  = c0 + wc + 16 * nt + ln;
        int which = colg >> 10;          // uniform within the 16-col group
        int h     = (colg >> 6) & 15;    // uniform within the 16-col group
        int e     = colg & 63;
        const float* bp = (which == 0) ? bq : (which == 1) ? bk : bv;
        float bias = bp[h * DH_ + e];
        if (which < 2){
            f16* op = (which == 0) ? Qh : Kh;
            float scale = (which == 0) ? QSCALE : 1.0f;
            #pragma unroll
            for (int mt = 0; mt < 4; ++mt)
                #pragma unroll
                for (int r = 0; r < 4; ++r){
                    int sg = m0 + wr + 16 * mt + 4 * quad + r;
                    int b  = sg >> 11;
                    int s  = sg & (S_ - 1);
                    float val = (acc[mt][nt][r] * INV64 + bias) * scale;
                    op[((size_t)(b * H_ + h) * S_ + s) * DH_ + e] = (f16)val;
                }
        } else {
            // V: write transposed Vt[bh][e][t]; 4 consecutive s -> 8B store
            #pragma unroll
            for (int mt = 0; mt < 4; ++mt){
                int sg0 = m0 + wr + 16 * mt + 4 * quad;
                int b   = sg0 >> 11;
                int s0  = sg0 & (S_ - 1);
                u16 p[4];
                #pragma unroll
                for (int r = 0; r < 4; ++r)
                    p[r] = h_bits((f16)(acc[mt][nt][r] * INV64 + bias));
                uint2 pk;
                pk.x = p[0] | ((u32)p[1] << 16);
                pk.y = p[2] | ((u32)p[3] << 16);
                *(uint2*)((u16*)Vt + ((size_t)((b * H_ + h) * DH_ + e)) * S_ + s0) = pk;
            }
        }
    }
}

// ---------------------------------------------------------------------------
// Kernel 3: attention.  R10: exact R7 64-wide-tile loop structure (proven:
// 52 VGPR, no scratch -- both 128-wide variants generated 434 MB of scratch
// writes regardless of score-array slicing), plus two safe levers:
//  (a) XCD swizzle: grid (hb, pair) -> linear id = hb + 32*pair, so
//      id mod 8 = hb mod 8: all 32 blocks of one (b,h) land on ONE XCD,
//      all co-resident; per-XCD working set 4 bh x 768 KB = 3 MB < 4 MB L2.
//      K/V prefetch latency becomes L2-hit (~200 cyc), not HBM (~900).
//  (b) diagonal-only masking: qbase and subtile starts are multiples of 16
//      -> exactly one partial subtile per wave; all other PV subtiles skip
//      the 8 cmp+cndmask (wave-uniform branch).
// S^T = K·Q^T via mfma_16x16x32_f16; C-layout of S^T is the PV A-layout,
// so P stays in registers.  Denominator over ALL t (reference softmaxes the
// full row); PV only t<=s (post-softmax tril, no renorm).  No max-tracking
// (logits provably tiny; base-2 exp, 0.125*log2e folded into Q upstream).
// grid (32 hb, 32 pairs), block 256.  LDS 18.4 KB.
// ---------------------------------------------------------------------------
#define AKS 72

__global__ __launch_bounds__(256, 4) void attn_kernel(
    const f16* __restrict__ Qh, const f16* __restrict__ Kh,
    const f16* __restrict__ Vt, float* __restrict__ Out)
{
    __shared__ u16 Ks[64 * AKS];   // K tile [t][e]
    __shared__ u16 Vs[64 * AKS];   // V tile [e][t]

    const int tid  = threadIdx.x;
    const int lane = tid & 63;
    const int w    = tid >> 6;
    const int quad = lane >> 4;
    const int ln   = lane & 15;
    const int hb   = blockIdx.x;            // b*H + h  (XCD = hb % 8)
    const int i    = blockIdx.y;            // pair index
    const int h    = hb & 15;
    const int b    = hb >> 4;
    const int bh   = hb;
    const int sub  = w & 1;
    const int qbase = (w >> 1) ? (S_ - 32 * (i + 1) + 16 * sub)
                               : (32 * i + 16 * sub);
    const int vmax  = S_ - 32 * i - 1;      // highest t any wave's PV needs

    const u16* Qg = (const u16*)Qh + (size_t)bh * S_ * DH_;
    const u16* Kg = (const u16*)Kh + (size_t)bh * S_ * DH_;
    const u16* Vg = (const u16*)Vt + (size_t)bh * DH_ * S_;

    // Q fragments straight from global (B-operand: n=q=ln, k=d=32ks+8quad+j)
    half8 qf[2];
    #pragma unroll
    for (int ks = 0; ks < 2; ++ks)
        qf[ks] = __builtin_bit_cast(half8,
            *(const uint4*)(Qg + (size_t)(qbase + ln) * DH_ + 32 * ks + 8 * quad));

    // staging coords: thread covers K rows kr,kr+32 / V rows (e) kr,kr+32
    const int kr = tid >> 3;
    const int kc = (tid & 7) * 8;

    // prefetch tile 0 into registers
    uint4 kA = *(const uint4*)(Kg + (size_t)kr * DH_ + kc);
    uint4 kB = *(const uint4*)(Kg + (size_t)(kr + 32) * DH_ + kc);
    uint4 vA = *(const uint4*)(Vg + (size_t)kr * S_ + kc);
    uint4 vB = *(const uint4*)(Vg + (size_t)(kr + 32) * S_ + kc);

    float l_r = 0.f;
    f32x4 o_acc[4];
    #pragma unroll
    for (int nt = 0; nt < 4; ++nt) o_acc[nt] = (f32x4){0.f, 0.f, 0.f, 0.f};

    const int qrow   = qbase + ln;     // this lane's q (n-dim)
    const int pv_lim = qbase + 15;     // wave-uniform PV bound

    for (int t0 = 0; t0 < S_; t0 += 64){
        __syncthreads();               // all waves done reading prev tile
        *(uint4*)&Ks[kr * AKS + kc]        = kA;
        *(uint4*)&Ks[(kr + 32) * AKS + kc] = kB;
        if (t0 <= vmax){
            *(uint4*)&Vs[kr * AKS + kc]        = vA;
            *(uint4*)&Vs[(kr + 32) * AKS + kc] = vB;
        }
        // prefetch tile t0+64 (hidden behind this tile's compute)
        const int tn = t0 + 64;
        if (tn < S_){
            kA = *(const uint4*)(Kg + (size_t)(tn + kr) * DH_ + kc);
            kB = *(const uint4*)(Kg + (size_t)(tn + kr + 32) * DH_ + kc);
            if (tn <= vmax){
                vA = *(const uint4*)(Vg + (size_t)kr * S_ + tn + kc);
                vB = *(const uint4*)(Vg + (size_t)(kr + 32) * S_ + tn + kc);
            }
        }
        __syncthreads();               // LDS tile ready

        // S^T tile: A = K frags (m=t), B = Q frags (n=q), K=32 over d
        f32x4 sc[4];
        #pragma unroll
        for (int mt = 0; mt < 4; ++mt) sc[mt] = (f32x4){0.f, 0.f, 0.f, 0.f};
        #pragma unroll
        for (int ks = 0; ks < 2; ++ks)
            #pragma unroll
            for (int mt = 0; mt < 4; ++mt){
                half8 kf = __builtin_bit_cast(half8,
                    *(const uint4*)&Ks[(16 * mt + ln) * AKS + 32 * ks + 8 * quad]);
                sc[mt] = __builtin_amdgcn_mfma_f32_16x16x32_f16(kf, qf[ks], sc[mt], 0, 0, 0);
            }

        // p = exp2(s); denominator = plain running row-sum over ALL t
        #pragma unroll
        for (int mt = 0; mt < 4; ++mt)
            #pragma unroll
            for (int r = 0; r < 4; ++r)
                sc[mt][r] = EXP2(sc[mt][r]);
        float s = ((sc[0][0] + sc[0][1] + sc[0][2] + sc[0][3]) +
                   (sc[1][0] + sc[1][1] + sc[1][2] + sc[1][3])) +
                  ((sc[2][0] + sc[2][1] + sc[2][2] + sc[2][3]) +
                   (sc[3][0] + sc[3][1] + sc[3][2] + sc[3][3]));
        s += __shfl_xor(s, 16);
        s += __shfl_xor(s, 32);
        l_r += s;

        // PV per 16-t subtile; only the subtile starting AT qbase is partial
        #pragma unroll
        for (int mt = 0; mt < 4; ++mt){
            const int ts = t0 + 16 * mt;
            if (ts <= pv_lim){         // wave-uniform
                half4 pf;
                if (ts == qbase){      // wave-uniform: the one partial subtile
                    int tb = ts + 4 * quad;
                    #pragma unroll
                    for (int r = 0; r < 4; ++r)
                        pf[r] = (tb + r > qrow) ? (f16)0.f : (f16)sc[mt][r];
                } else {               // fully below diagonal: plain convert
                    #pragma unroll
                    for (int r = 0; r < 4; ++r)
                        pf[r] = (f16)sc[mt][r];
                }
                #pragma unroll
                for (int nt = 0; nt < 4; ++nt){
                    half4 vf = __builtin_bit_cast(half4,
                        *(const uint2*)&Vs[(16 * nt + ln) * AKS + 16 * mt + 4 * quad]);
                    o_acc[nt] = __builtin_amdgcn_mfma_f32_16x16x16f16(pf, vf, o_acc[nt], 0, 0, 0);
                }
            }
        }
    }

    // epilogue: o rows at q = qbase+4quad+r; l lives at lane ln=row
    #pragma unroll
    for (int r = 0; r < 4; ++r){
        float lv  = __shfl(l_r, (lane & 48) | (4 * quad + r));
        float inv = 1.0f / lv;
        int sg = qbase + 4 * quad + r;
        float* op = Out + ((size_t)b * S_ + sg) * D_ + h * DH_;
        #pragma unroll
        for (int nt = 0; nt < 4; ++nt)
            op[16 * nt + ln] = o_acc[nt][r] * inv;
    }
}

// ---------------------------------------------------------------------------
extern "C" void kernel_launch(void* const* d_in, const int* in_sizes, int n_in,
                              void* d_out, int out_size, void* d_ws, size_t ws_size,
                              hipStream_t stream)
{
    const float* X  = (const float*)d_in[0];
    const float* Wq = (const float*)d_in[1];
    const float* bq = (const float*)d_in[2];
    const float* Wk = (const float*)d_in[3];
    const float* bk = (const float*)d_in[4];
    const float* Wv = (const float*)d_in[5];
    const float* bv = (const float*)d_in[6];
    float* out = (float*)d_out;

    // workspace (46 MiB): Wt | Qh | Kh | Vt | Xhi | Xlo
    u16* Wt  = (u16*)d_ws;                    // 3,145,728 u16
    f16* Qh  = (f16*)(Wt + 3145728);
    f16* Kh  = Qh + 4194304;
    f16* Vt  = Kh + 4194304;
    u16* Xhi = (u16*)(Vt + 4194304);
    u16* Xlo = Xhi + 4194304;

    prep_kernel<<<dim3(4096 + 768), 256, 0, stream>>>(X, Wq, Wk, Wv, Xhi, Xlo, Wt);
    proj_kernel<<<dim3(32, 24), 256, 0, stream>>>(Xhi, Xlo, Wt, bq, bk, bv, Qh, Kh, Vt);
    attn_kernel<<<dim3(32, 32), 256, 0, stream>>>(Qh, Kh, Vt, out);
}